// Round 3
// baseline (1139.572 us; speedup 1.0000x reference)
//
#include <hip/hip_runtime.h>
#include <hip/hip_bf16.h>
#include <cstdint>
#include <cstddef>

#define Sd 1024
#define Dd 512
#define Hd 8
#define Fd 2048
#define Bd 8
#define EPSf 1e-3f

typedef __bf16 bf16x8 __attribute__((ext_vector_type(8)));
typedef float f32x4 __attribute__((ext_vector_type(4)));
typedef __attribute__((address_space(3))) unsigned int lds_u32;
typedef __attribute__((address_space(1))) const unsigned int gl_u32;

#define BM 128
#define BN 128
#define BK 32

enum { EPI_BF16 = 0, EPI_F32 = 1, EPI_BNPRELU = 2, EPI_F32ACC = 3 };

__device__ __forceinline__ void gl_lds16(const void* g, void* l) {
  __builtin_amdgcn_global_load_lds((gl_u32*)g, (lds_u32*)l, 16, 0, 0);
}

// ---- m97-structure BT-GEMM: C[M,N] = epi(alpha * A @ Bt^T + bias) ----
// A [M,K] bf16 row-major, Bt [N,K] bf16 row-major. z1 = z>>zshift, z2 = low bits.
template <int EPI, int BIASROW>
__global__ __launch_bounds__(256, 2) void bt_gemm(
    const __hip_bfloat16* __restrict__ A_, int lda, size_t sA1, size_t sA2,
    const __hip_bfloat16* __restrict__ B_, int ldb, size_t sB1, size_t sB2,
    const float* __restrict__ bias_, size_t sBi1, size_t sBi2,
    void* __restrict__ C_, int ldc, size_t sC1, size_t sC2,
    int K, float alpha, int zshift,
    const float* __restrict__ bn_g, const float* __restrict__ bn_b,
    const float* __restrict__ bn_m, const float* __restrict__ bn_v,
    const float* __restrict__ pa) {
  __shared__ __hip_bfloat16 As[BM * BK];
  __shared__ __hip_bfloat16 Bs[BN * BK];

  const int tid = threadIdx.x;
  const int z = blockIdx.z;
  const int z1 = z >> zshift;
  const int z2 = z & ((1 << zshift) - 1);
  const int m0 = blockIdx.y * BM;
  const int n0 = blockIdx.x * BN;

  const __hip_bfloat16* A = A_ + (size_t)z1 * sA1 + (size_t)z2 * sA2;
  const __hip_bfloat16* Bt = B_ + (size_t)z1 * sB1 + (size_t)z2 * sB2;
  const float* bi = bias_ ? bias_ + (size_t)z1 * sBi1 + (size_t)z2 * sBi2 : nullptr;

  const int lane = tid & 63;
  const int wv = tid >> 6;
  const int wm = (wv >> 1) * 64;
  const int wn = (wv & 1) * 64;
  const int fr = lane & 15;
  const int kg = lane >> 4;

  // staging: slot s in [0,512): row = s>>2, 16B chunk = s&3.
  const int srow = tid >> 2, sch = tid & 3;
  const size_t ldab = (size_t)lda * 2, ldbb = (size_t)ldb * 2;
  const char* Ap = (const char*)A + (size_t)(m0 + srow) * ldab + sch * 16;
  const char* Ap2 = Ap + 64 * ldab;
  const char* Bp = (const char*)Bt + (size_t)(n0 + srow) * ldbb + sch * 16;
  const char* Bp2 = Bp + 64 * ldbb;
  char* lA = (char*)As + tid * 16;
  char* lB = (char*)Bs + tid * 16;

  f32x4 acc[4][4] = {};

  for (int kt = 0; kt < K; kt += BK) {
    const size_t kb = (size_t)kt * 2;
    gl_lds16(Ap + kb, lA);
    gl_lds16(Ap2 + kb, lA + 4096);
    gl_lds16(Bp + kb, lB);
    gl_lds16(Bp2 + kb, lB + 4096);
    __syncthreads();

    bf16x8 afr[4], bfr[4];
#pragma unroll
    for (int mi = 0; mi < 4; ++mi)
      afr[mi] = *reinterpret_cast<const bf16x8*>(As + (wm + mi * 16 + fr) * BK + kg * 8);
#pragma unroll
    for (int ni = 0; ni < 4; ++ni)
      bfr[ni] = *reinterpret_cast<const bf16x8*>(Bs + (wn + ni * 16 + fr) * BK + kg * 8);
#pragma unroll
    for (int mi = 0; mi < 4; ++mi)
#pragma unroll
      for (int ni = 0; ni < 4; ++ni)
        acc[mi][ni] = __builtin_amdgcn_mfma_f32_16x16x32_bf16(afr[mi], bfr[ni], acc[mi][ni], 0, 0, 0);
    __syncthreads();
  }

  // epilogue: C/D layout col=lane&15, row=(lane>>4)*4+j  [m89-verified]
  char* C = (char*)C_ + ((size_t)z1 * sC1 + (size_t)z2 * sC2) *
                            ((EPI == EPI_F32 || EPI == EPI_F32ACC) ? 4 : 2);
#pragma unroll
  for (int ni = 0; ni < 4; ++ni) {
    const int col = n0 + wn + ni * 16 + fr;
    float bcol = 0.f, scale = 0.f, shift = 0.f;
    if (bi && !BIASROW) bcol = bi[col];
    if (EPI == EPI_BNPRELU) {
      scale = bn_g[col] * rsqrtf(bn_v[col] + EPSf);
      shift = bn_b[col] - bn_m[col] * scale;
    }
#pragma unroll
    for (int mi = 0; mi < 4; ++mi) {
      const int rb = m0 + wm + mi * 16 + kg * 4;
#pragma unroll
      for (int j = 0; j < 4; ++j) {
        const int row = rb + j;
        float v = acc[mi][ni][j] * alpha + bcol;
        if (BIASROW) v += bi[row];
        if (EPI == EPI_F32) {
          ((float*)C)[(size_t)row * ldc + col] = v;
        } else if (EPI == EPI_F32ACC) {
          float* cp = (float*)C + (size_t)row * ldc + col;
          *cp = *cp + v;
        } else if (EPI == EPI_BF16) {
          ((__hip_bfloat16*)C)[(size_t)row * ldc + col] = __float2bfloat16(v);
        } else {
          v = v * scale + shift;
          const float a = pa[(size_t)(row & (Sd - 1)) * Fd + col];
          v = v > 0.f ? v : a * v;
          ((__hip_bfloat16*)C)[(size_t)row * ldc + col] = __float2bfloat16(v);
        }
      }
    }
  }
}

// ---- transpose + convert: src [K][N] f32 -> dst [N][Kfull] bf16 ----
__global__ __launch_bounds__(256) void tconv(const float* __restrict__ src,
                                             __hip_bfloat16* __restrict__ dst,
                                             int N, int Kfull, size_t sIn, size_t sOut) {
  __shared__ __hip_bfloat16 t[64][65];
  const float* s = src + (size_t)blockIdx.z * sIn;
  __hip_bfloat16* d = dst + (size_t)blockIdx.z * sOut;
  const int k0 = blockIdx.y * 64, n0 = blockIdx.x * 64;
  const int tid = threadIdx.x;
#pragma unroll
  for (int i = 0; i < 4; ++i) {
    int slot = tid + i * 256;
    int r = slot >> 4, c = (slot & 15) * 4;
    const float4 v = *reinterpret_cast<const float4*>(s + (size_t)(k0 + r) * N + n0 + c);
    t[c + 0][r] = __float2bfloat16(v.x);
    t[c + 1][r] = __float2bfloat16(v.y);
    t[c + 2][r] = __float2bfloat16(v.z);
    t[c + 3][r] = __float2bfloat16(v.w);
  }
  __syncthreads();
#pragma unroll
  for (int i = 0; i < 2; ++i) {
    int slot = tid + i * 256;
    int n = slot >> 3, kc = (slot & 7) * 8;
    __hip_bfloat16 tmp[8];
#pragma unroll
    for (int j = 0; j < 8; ++j) tmp[j] = t[n][kc + j];
    *reinterpret_cast<float4*>(d + (size_t)(n0 + n) * Kfull + k0 + kc) =
        *reinterpret_cast<const float4*>(tmp);
  }
}

// ---- f32 -> bf16 elementwise, 3 tensors of 4M elems; grid(2048,3) ----
__global__ __launch_bounds__(256) void conv3(const float* __restrict__ s0, const float* __restrict__ s1,
                                             const float* __restrict__ s2,
                                             __hip_bfloat16* __restrict__ d0, __hip_bfloat16* __restrict__ d1,
                                             __hip_bfloat16* __restrict__ d2) {
  const float* s = blockIdx.y == 0 ? s0 : (blockIdx.y == 1 ? s1 : s2);
  __hip_bfloat16* d = blockIdx.y == 0 ? d0 : (blockIdx.y == 1 ? d1 : d2);
  const size_t i = (size_t)blockIdx.x * 256 + threadIdx.x;
  const float4 a = reinterpret_cast<const float4*>(s)[2 * i];
  const float4 b = reinterpret_cast<const float4*>(s)[2 * i + 1];
  __hip_bfloat16 tmp[8] = {
      __float2bfloat16(a.x), __float2bfloat16(a.y), __float2bfloat16(a.z), __float2bfloat16(a.w),
      __float2bfloat16(b.x), __float2bfloat16(b.y), __float2bfloat16(b.z), __float2bfloat16(b.w)};
  *reinterpret_cast<float4*>(d + 8 * i) = *reinterpret_cast<const float4*>(tmp);
}

__global__ __launch_bounds__(256) void copy_bias2(const float* __restrict__ a,
                                                  const float* __restrict__ b,
                                                  float* __restrict__ d) {
  const int i = blockIdx.x * 256 + threadIdx.x;  // grid 16 -> 4096 each
  d[i] = a[i];
  d[4096 + i] = b[i];
}

// ---- reductions ----
__device__ inline float wave_max(float v) {
#pragma unroll
  for (int o = 32; o > 0; o >>= 1) v = fmaxf(v, __shfl_xor(v, o));
  return v;
}
__device__ inline float wave_sum(float v) {
#pragma unroll
  for (int o = 32; o > 0; o >>= 1) v += __shfl_xor(v, o);
  return v;
}

__device__ inline float b2f(unsigned short u) {
  unsigned x = ((unsigned)u) << 16; float f; __builtin_memcpy(&f, &x, 4); return f;
}
__device__ inline unsigned short f2b(float f) {
  __hip_bfloat16 h = __float2bfloat16(f); unsigned short u; __builtin_memcpy(&u, &h, 2); return u;
}

// softmax over rows of sc[b][1024][1024] bf16, in place. grid(1024, Bd), 256 thr.
__global__ __launch_bounds__(256) void softmax_bf16(__hip_bfloat16* __restrict__ sc) {
  const int tid = threadIdx.x;
  __hip_bfloat16* rowp = sc + ((size_t)blockIdx.y << 20) + ((size_t)blockIdx.x << 10);
  const ushort4 r = reinterpret_cast<const ushort4*>(rowp)[tid];
  const float v0 = b2f(r.x), v1 = b2f(r.y), v2 = b2f(r.z), v3 = b2f(r.w);
  __shared__ float red[8];
  float mx = fmaxf(fmaxf(v0, v1), fmaxf(v2, v3));
  mx = wave_max(mx);
  if ((tid & 63) == 0) red[tid >> 6] = mx;
  __syncthreads();
  mx = fmaxf(fmaxf(red[0], red[1]), fmaxf(red[2], red[3]));
  const float e0 = __expf(v0 - mx), e1 = __expf(v1 - mx);
  const float e2 = __expf(v2 - mx), e3 = __expf(v3 - mx);
  float s = wave_sum(e0 + e1 + e2 + e3);
  if ((tid & 63) == 0) red[4 + (tid >> 6)] = s;
  __syncthreads();
  const float inv = 1.f / (red[4] + red[5] + red[6] + red[7]);
  ushort4 o;
  o.x = f2b(e0 * inv); o.y = f2b(e1 * inv); o.z = f2b(e2 * inv); o.w = f2b(e3 * inv);
  reinterpret_cast<ushort4*>(rowp)[tid] = o;
}

// out = LN(Xa + Xb)*gamma + beta (rows of 512); optional bf16 copy. grid(8192), 256 thr.
__global__ __launch_bounds__(256) void add_ln(const float* __restrict__ Xa, const float* __restrict__ Xb,
                                              const float* __restrict__ gamma, const float* __restrict__ beta,
                                              float* __restrict__ out, __hip_bfloat16* __restrict__ outb) {
  const int tid = threadIdx.x;
  const size_t base = (size_t)blockIdx.x * Dd;
  const float2 a = reinterpret_cast<const float2*>(Xa + base)[tid];
  const float2 b = reinterpret_cast<const float2*>(Xb + base)[tid];
  const float r0 = a.x + b.x, r1 = a.y + b.y;
  float s = wave_sum(r0 + r1);
  float q = wave_sum(r0 * r0 + r1 * r1);
  __shared__ float rs[4], rq[4];
  if ((tid & 63) == 0) { rs[tid >> 6] = s; rq[tid >> 6] = q; }
  __syncthreads();
  const float mean = (rs[0] + rs[1] + rs[2] + rs[3]) * (1.f / Dd);
  const float msq = (rq[0] + rq[1] + rq[2] + rq[3]) * (1.f / Dd);
  const float inv = rsqrtf(msq - mean * mean + EPSf);
  const int c = tid * 2;
  const float y0 = (r0 - mean) * inv * gamma[c] + beta[c];
  const float y1 = (r1 - mean) * inv * gamma[c + 1] + beta[c + 1];
  out[base + c] = y0;
  out[base + c + 1] = y1;
  if (outb) {
    outb[base + c] = __float2bfloat16(y0);
    outb[base + c + 1] = __float2bfloat16(y1);
  }
}

extern "C" void kernel_launch(void* const* d_in, const int* in_sizes, int n_in,
                              void* d_out, int out_size, void* d_ws, size_t ws_size,
                              hipStream_t stream) {
  const float* Q = (const float*)d_in[0];
  const float* K = (const float*)d_in[1];
  const float* V = (const float*)d_in[2];
  const float* WQ = (const float*)d_in[3];
  const float* bQ = (const float*)d_in[4];
  const float* WK = (const float*)d_in[5];
  const float* bK = (const float*)d_in[6];
  const float* WV = (const float*)d_in[7];
  const float* bV = (const float*)d_in[8];
  const float* Wo = (const float*)d_in[9];
  const float* bo = (const float*)d_in[10];
  const float* W0 = (const float*)d_in[11];
  const float* b0 = (const float*)d_in[12];
  const float* g0 = (const float*)d_in[13];
  const float* be0 = (const float*)d_in[14];
  const float* m0 = (const float*)d_in[15];
  const float* v0 = (const float*)d_in[16];
  const float* a0 = (const float*)d_in[17];
  const float* W1 = (const float*)d_in[18];
  const float* b1 = (const float*)d_in[19];
  const float* g1 = (const float*)d_in[20];
  const float* be1 = (const float*)d_in[21];
  const float* m1 = (const float*)d_in[22];
  const float* v1 = (const float*)d_in[23];
  const float* a1 = (const float*)d_in[24];
  const float* W2 = (const float*)d_in[25];
  const float* b2 = (const float*)d_in[26];
  const float* ln0g = (const float*)d_in[27];
  const float* ln0b = (const float*)d_in[28];
  const float* ln1g = (const float*)d_in[29];
  const float* ln1b = (const float*)d_in[30];

  typedef __hip_bfloat16 bf;
  const size_t MB = 1u << 20;
  char* ws = (char*)d_ws;
  // -------- head-major layout (peak ~116 MiB) --------
  bf* qbf = (bf*)(ws);                   // [8][1024][512]   0..8M
  bf* kbf = (bf*)(ws + 8 * MB);          // 8..16M
  bf* vbf = (bf*)(ws + 16 * MB);         // 16..24M
  bf* wqt = (bf*)(ws + 24 * MB);         // [8][512][512]    24..28M
  bf* wkt = (bf*)(ws + 28 * MB);         // 28..32M
  bf* wvt = (bf*)(ws + 32 * MB);         // 32..36M
  bf* wot = (bf*)(ws + 36 * MB);         // [512][4096]      36..40M
  float* bqk = (float*)(ws + 40 * MB);   // [2][8][512]      40..40M+32K
  float* mha = (float*)(ws + 44 * MB);   // [8192][512] f32  44..60M
  bf* qh = (bf*)(ws + 60 * MB);          // [8192][512]      60..68M (per head)
  bf* kh = (bf*)(ws + 68 * MB);          // 68..76M
  bf* vht = (bf*)(ws + 76 * MB);         // [8][512][1024]   76..84M
  bf* sc = (bf*)(ws + 84 * MB);          // [8][1024][1024]  84..100M
  bf* ctx = (bf*)(ws + 100 * MB);        // [8192][512]      100..108M
  // -------- post-attention (dead-region reuse) --------
  float* xbuf = (float*)(ws + 60 * MB);  // [8192][512]  (over qh/kh)
  bf* xb = (bf*)(ws + 76 * MB);          // [8192][512]  (over vht)
  bf* w0t = (bf*)(ws);                   // [2048][512]   0..2M
  bf* w1t = (bf*)(ws + 2 * MB);          // [2048][2048]  2..10M
  bf* w2t = (bf*)(ws + 10 * MB);         // [512][2048]   10..12M
  bf* h0 = (bf*)(ws + 12 * MB);          // [8192][2048]  12..44M
  bf* h1 = (bf*)(ws + 84 * MB);          // [8192][2048]  84..116M (over sc/ctx)
  float* ff = (float*)(ws + 44 * MB);    // [8192][512]   (over mha, dead after LN0)

  const size_t SD = (size_t)Sd * Dd;     // 524288
  const size_t DD = (size_t)Dd * Dd;     // 262144
  const size_t SS = (size_t)Sd * Sd;     // 1048576
  const size_t E8M = 8 * MB / 2;         // 4194304 elems (8 MiB of bf16)
  const float* np = nullptr;

  // all-batch bf16 conversion + weights
  conv3<<<dim3(2048, 3), 256, 0, stream>>>(Q, K, V, qbf, kbf, vbf);
  tconv<<<dim3(8, 8, 8), 256, 0, stream>>>(WQ, wqt, Dd, Dd, DD, DD);
  tconv<<<dim3(8, 8, 8), 256, 0, stream>>>(WK, wkt, Dd, Dd, DD, DD);
  tconv<<<dim3(8, 8, 8), 256, 0, stream>>>(WV, wvt, Dd, Dd, DD, DD);
  tconv<<<dim3(8, 64, 1), 256, 0, stream>>>(Wo, wot, Dd, Hd * Dd, 0, 0);
  copy_bias2<<<16, 256, 0, stream>>>(bQ, bK, bqk);

  for (int h = 0; h < Hd; ++h) {
    // q/k proj, all batches stacked: z=0 -> qh = qbf @ wqt_h^T + bQ_h ; z=1 -> kh
    bt_gemm<EPI_BF16, 0><<<dim3(4, 64, 2), 256, 0, stream>>>(
        qbf, Dd, E8M, 0, wqt + (size_t)h * DD, Dd, 2 * DD, 0, bqk + h * Dd, 4096, 0,
        qh, Dd, E8M, 0, Dd, 1.f, 0, np, np, np, np, np);
    // vht[b] = wvt_h @ vbf[b]^T + bV_h (row bias): [512][1024] per batch
    bt_gemm<EPI_BF16, 1><<<dim3(8, 4, 8), 256, 0, stream>>>(
        wvt + (size_t)h * DD, Dd, 0, 0, vbf, Dd, SD, 0, bV + h * Dd, 0, 0,
        vht, Sd, SD, 0, Dd, 1.f, 0, np, np, np, np, np);
    // scores[b] = (qh[b] @ kh[b]^T) / D
    bt_gemm<EPI_BF16, 0><<<dim3(8, 8, 8), 256, 0, stream>>>(
        qh, Dd, SD, 0, kh, Dd, SD, 0, np, 0, 0,
        sc, Sd, SS, 0, Dd, 1.f / (float)Dd, 0, np, np, np, np, np);
    softmax_bf16<<<dim3(Sd, Bd), 256, 0, stream>>>(sc);
    // ctx[b] = probs[b] @ vht[b]^T
    bt_gemm<EPI_BF16, 0><<<dim3(4, 8, 8), 256, 0, stream>>>(
        sc, Sd, SS, 0, vht, Sd, SD, 0, np, 0, 0,
        ctx, Dd, SD, 0, Sd, 1.f, 0, np, np, np, np, np);
    // mha (+)= ctx @ Wo_h^T ; h==0 initializes with bias bo
    if (h == 0) {
      bt_gemm<EPI_F32, 0><<<dim3(4, 64, 1), 256, 0, stream>>>(
          ctx, Dd, 0, 0, wot, Hd * Dd, 0, 0, bo, 0, 0,
          mha, Dd, 0, 0, Dd, 1.f, 0, np, np, np, np, np);
    } else {
      bt_gemm<EPI_F32ACC, 0><<<dim3(4, 64, 1), 256, 0, stream>>>(
          ctx, Dd, 0, 0, wot + (size_t)h * Dd, Hd * Dd, 0, 0, np, 0, 0,
          mha, Dd, 0, 0, Dd, 1.f, 0, np, np, np, np, np);
    }
  }

  // x = LN(Q + mha)
  add_ln<<<Bd * Sd, 256, 0, stream>>>(Q, mha, ln0g, ln0b, xbuf, xb);

  // FF weights
  tconv<<<dim3(32, 8, 1), 256, 0, stream>>>(W0, w0t, Fd, Dd, 0, 0);
  tconv<<<dim3(32, 32, 1), 256, 0, stream>>>(W1, w1t, Fd, Fd, 0, 0);
  tconv<<<dim3(8, 32, 1), 256, 0, stream>>>(W2, w2t, Dd, Fd, 0, 0);

  bt_gemm<EPI_BNPRELU, 0><<<dim3(16, 64, 1), 256, 0, stream>>>(
      xb, Dd, 0, 0, w0t, Dd, 0, 0, b0, 0, 0,
      h0, Fd, 0, 0, Dd, 1.f, 0, g0, be0, m0, v0, a0);
  bt_gemm<EPI_BNPRELU, 0><<<dim3(16, 64, 1), 256, 0, stream>>>(
      h0, Fd, 0, 0, w1t, Fd, 0, 0, b1, 0, 0,
      h1, Fd, 0, 0, Fd, 1.f, 0, g1, be1, m1, v1, a1);
  bt_gemm<EPI_F32, 0><<<dim3(4, 64, 1), 256, 0, stream>>>(
      h1, Fd, 0, 0, w2t, Fd, 0, 0, b2, 0, 0,
      ff, Dd, 0, 0, Fd, 1.f, 0, np, np, np, np, np);
  add_ln<<<Bd * Sd, 256, 0, stream>>>(xbuf, ff, ln1g, ln1b, (float*)d_out, nullptr);
}

// Round 4
// 913.134 us; speedup vs baseline: 1.2480x; 1.2480x over previous
//
#include <hip/hip_runtime.h>
#include <hip/hip_bf16.h>
#include <cstdint>
#include <cstddef>

#define Sd 1024
#define Dd 512
#define Hd 8
#define Fd 2048
#define Bd 8
#define EPSf 1e-3f

typedef __bf16 bf16x8 __attribute__((ext_vector_type(8)));
typedef float f32x4 __attribute__((ext_vector_type(4)));
typedef __attribute__((address_space(3))) unsigned int lds_u32;
typedef __attribute__((address_space(1))) const unsigned int gl_u32;

#define BM 128
#define BN 128
#define BK 32

enum { EPI_BF16 = 0, EPI_F32 = 1, EPI_BNPRELU = 2, EPI_SCORES = 3 };

__device__ __forceinline__ void gl_lds16(const void* g, void* l) {
  __builtin_amdgcn_global_load_lds((gl_u32*)g, (lds_u32*)l, 16, 0, 0);
}

// ---- m97-structure BT-GEMM: C[M,N] = epi(alpha * A @ Bt^T + bias) ----
// A [M,K] bf16 row-major, Bt [N,K] bf16 row-major. z1 = z>>zshift, z2 = low bits.
// EPI_SCORES: v = (acc + u[row] + w[col] + c) * alpha, with u = bn_g + z2*8192,
// w = bn_b + z2*8192, c = bn_m[z2]  (M, N must be 1024 here).
template <int EPI>
__global__ __launch_bounds__(256, 2) void bt_gemm(
    const __hip_bfloat16* __restrict__ A_, int lda, size_t sA1, size_t sA2,
    const __hip_bfloat16* __restrict__ B_, int ldb, size_t sB1, size_t sB2,
    const float* __restrict__ bias_, size_t sBi1, size_t sBi2,
    void* __restrict__ C_, int ldc, size_t sC1, size_t sC2,
    int K, float alpha, int zshift,
    const float* __restrict__ bn_g, const float* __restrict__ bn_b,
    const float* __restrict__ bn_m, const float* __restrict__ bn_v,
    const float* __restrict__ pa) {
  __shared__ __hip_bfloat16 As[BM * BK];
  __shared__ __hip_bfloat16 Bs[BN * BK];

  const int tid = threadIdx.x;
  const int z = blockIdx.z;
  const int z1 = z >> zshift;
  const int z2 = z & ((1 << zshift) - 1);
  const int m0 = blockIdx.y * BM;
  const int n0 = blockIdx.x * BN;

  const __hip_bfloat16* A = A_ + (size_t)z1 * sA1 + (size_t)z2 * sA2;
  const __hip_bfloat16* Bt = B_ + (size_t)z1 * sB1 + (size_t)z2 * sB2;
  const float* bi = bias_ ? bias_ + (size_t)z1 * sBi1 + (size_t)z2 * sBi2 : nullptr;

  const int lane = tid & 63;
  const int wv = tid >> 6;
  const int wm = (wv >> 1) * 64;
  const int wn = (wv & 1) * 64;
  const int fr = lane & 15;
  const int kg = lane >> 4;

  // staging: slot s in [0,512): row = s>>2, 16B chunk = s&3.
  const int srow = tid >> 2, sch = tid & 3;
  const size_t ldab = (size_t)lda * 2, ldbb = (size_t)ldb * 2;
  const char* Ap = (const char*)A + (size_t)(m0 + srow) * ldab + sch * 16;
  const char* Ap2 = Ap + 64 * ldab;
  const char* Bp = (const char*)Bt + (size_t)(n0 + srow) * ldbb + sch * 16;
  const char* Bp2 = Bp + 64 * ldbb;
  char* lA = (char*)As + tid * 16;
  char* lB = (char*)Bs + tid * 16;

  f32x4 acc[4][4] = {};

  for (int kt = 0; kt < K; kt += BK) {
    const size_t kb = (size_t)kt * 2;
    gl_lds16(Ap + kb, lA);
    gl_lds16(Ap2 + kb, lA + 4096);
    gl_lds16(Bp + kb, lB);
    gl_lds16(Bp2 + kb, lB + 4096);
    __syncthreads();

    bf16x8 afr[4], bfr[4];
#pragma unroll
    for (int mi = 0; mi < 4; ++mi)
      afr[mi] = *reinterpret_cast<const bf16x8*>(As + (wm + mi * 16 + fr) * BK + kg * 8);
#pragma unroll
    for (int ni = 0; ni < 4; ++ni)
      bfr[ni] = *reinterpret_cast<const bf16x8*>(Bs + (wn + ni * 16 + fr) * BK + kg * 8);
#pragma unroll
    for (int mi = 0; mi < 4; ++mi)
#pragma unroll
      for (int ni = 0; ni < 4; ++ni)
        acc[mi][ni] = __builtin_amdgcn_mfma_f32_16x16x32_bf16(afr[mi], bfr[ni], acc[mi][ni], 0, 0, 0);
    __syncthreads();
  }

  // epilogue: C/D layout col=lane&15, row=(lane>>4)*4+j  [m89-verified]
  char* C = (char*)C_ + ((size_t)z1 * sC1 + (size_t)z2 * sC2) * ((EPI == EPI_F32) ? 4 : 2);
  const float cs = (EPI == EPI_SCORES) ? bn_m[z2] : 0.f;
#pragma unroll
  for (int ni = 0; ni < 4; ++ni) {
    const int col = n0 + wn + ni * 16 + fr;
    float bcol = 0.f, scale = 0.f, shift = 0.f;
    if (bi) bcol = bi[col];
    if (EPI == EPI_BNPRELU) {
      scale = bn_g[col] * rsqrtf(bn_v[col] + EPSf);
      shift = bn_b[col] - bn_m[col] * scale;
    }
    const float wcol = (EPI == EPI_SCORES) ? bn_b[z2 * 8192 + col] : 0.f;
#pragma unroll
    for (int mi = 0; mi < 4; ++mi) {
      const int rb = m0 + wm + mi * 16 + kg * 4;
#pragma unroll
      for (int j = 0; j < 4; ++j) {
        const int row = rb + j;
        float v;
        if (EPI == EPI_SCORES) {
          v = (acc[mi][ni][j] + bn_g[z2 * 8192 + row] + wcol + cs) * alpha;
          ((__hip_bfloat16*)C)[(size_t)row * ldc + col] = __float2bfloat16(v);
        } else {
          v = acc[mi][ni][j] * alpha + bcol;
          if (EPI == EPI_F32) {
            ((float*)C)[(size_t)row * ldc + col] = v;
          } else if (EPI == EPI_BF16) {
            ((__hip_bfloat16*)C)[(size_t)row * ldc + col] = __float2bfloat16(v);
          } else {
            v = v * scale + shift;
            const float a = pa[(size_t)(row & (Sd - 1)) * Fd + col];
            v = v > 0.f ? v : a * v;
            ((__hip_bfloat16*)C)[(size_t)row * ldc + col] = __float2bfloat16(v);
          }
        }
      }
    }
  }
}

// ---- transpose + convert: src [K][N] f32 -> dst [N][Kfull] bf16 ----
__global__ __launch_bounds__(256) void tconv(const float* __restrict__ src,
                                             __hip_bfloat16* __restrict__ dst,
                                             int N, int Kfull, size_t sIn, size_t sOut) {
  __shared__ __hip_bfloat16 t[64][65];
  const float* s = src + (size_t)blockIdx.z * sIn;
  __hip_bfloat16* d = dst + (size_t)blockIdx.z * sOut;
  const int k0 = blockIdx.y * 64, n0 = blockIdx.x * 64;
  const int tid = threadIdx.x;
#pragma unroll
  for (int i = 0; i < 4; ++i) {
    int slot = tid + i * 256;
    int r = slot >> 4, c = (slot & 15) * 4;
    const float4 v = *reinterpret_cast<const float4*>(s + (size_t)(k0 + r) * N + n0 + c);
    t[c + 0][r] = __float2bfloat16(v.x);
    t[c + 1][r] = __float2bfloat16(v.y);
    t[c + 2][r] = __float2bfloat16(v.z);
    t[c + 3][r] = __float2bfloat16(v.w);
  }
  __syncthreads();
#pragma unroll
  for (int i = 0; i < 2; ++i) {
    int slot = tid + i * 256;
    int n = slot >> 3, kc = (slot & 7) * 8;
    __hip_bfloat16 tmp[8];
#pragma unroll
    for (int j = 0; j < 8; ++j) tmp[j] = t[n][kc + j];
    *reinterpret_cast<float4*>(d + (size_t)(n0 + n) * Kfull + k0 + kc) =
        *reinterpret_cast<const float4*>(tmp);
  }
}

// ---- f32 -> bf16 elementwise; grid (nblk, ntensors), 8 elems/thread ----
__global__ __launch_bounds__(256) void conv3(const float* __restrict__ s0, const float* __restrict__ s1,
                                             const float* __restrict__ s2,
                                             __hip_bfloat16* __restrict__ d0, __hip_bfloat16* __restrict__ d1,
                                             __hip_bfloat16* __restrict__ d2) {
  const float* s = blockIdx.y == 0 ? s0 : (blockIdx.y == 1 ? s1 : s2);
  __hip_bfloat16* d = blockIdx.y == 0 ? d0 : (blockIdx.y == 1 ? d1 : d2);
  const size_t i = (size_t)blockIdx.x * 256 + threadIdx.x;
  const float4 a = reinterpret_cast<const float4*>(s)[2 * i];
  const float4 b = reinterpret_cast<const float4*>(s)[2 * i + 1];
  __hip_bfloat16 tmp[8] = {
      __float2bfloat16(a.x), __float2bfloat16(a.y), __float2bfloat16(a.z), __float2bfloat16(a.w),
      __float2bfloat16(b.x), __float2bfloat16(b.y), __float2bfloat16(b.z), __float2bfloat16(b.w)};
  *reinterpret_cast<float4*>(d + 8 * i) = *reinterpret_cast<const float4*>(tmp);
}

// ---- reductions ----
__device__ inline float wave_max(float v) {
#pragma unroll
  for (int o = 32; o > 0; o >>= 1) v = fmaxf(v, __shfl_xor(v, o));
  return v;
}
__device__ inline float wave_sum(float v) {
#pragma unroll
  for (int o = 32; o > 0; o >>= 1) v += __shfl_xor(v, o);
  return v;
}

__device__ inline float b2f(unsigned short u) {
  unsigned x = ((unsigned)u) << 16; float f; __builtin_memcpy(&f, &x, 4); return f;
}
__device__ inline unsigned short f2b(float f) {
  __hip_bfloat16 h = __float2bfloat16(f); unsigned short u; __builtin_memcpy(&u, &h, 2); return u;
}

// t1[hd] = sum_e WQ[h][d][e]*bK[h][e] (y=0); t2[hd] = sum_e WK[h][d][e]*bQ[h][e] (y=1)
// grid (1024, 2), 256 thr; wave per hd.
__global__ __launch_bounds__(256) void tvec(const float* __restrict__ WQ, const float* __restrict__ bK,
                                            const float* __restrict__ WK, const float* __restrict__ bQ,
                                            float* __restrict__ t1, float* __restrict__ t2) {
  const float* W = blockIdx.y == 0 ? WQ : WK;
  const float* bb = blockIdx.y == 0 ? bK : bQ;
  float* out = blockIdx.y == 0 ? t1 : t2;
  const int wv = threadIdx.x >> 6, lane = threadIdx.x & 63;
  const int hd = blockIdx.x * 4 + wv;
  const int h = hd >> 9;
  float acc = 0.f;
#pragma unroll
  for (int j = 0; j < 8; ++j) {
    const int e = lane + 64 * j;
    acc += W[(size_t)hd * 512 + e] * bb[h * 512 + e];
  }
  acc = wave_sum(acc);
  if (lane == 0) out[hd] = acc;
}

// u[h][row] = Q[row]·t1[h], w[h][row] = K[row]·t2[h]. grid (8192), 256 thr.
__global__ __launch_bounds__(256) void uw_kernel(const float* __restrict__ Q, const float* __restrict__ K,
                                                 const float* __restrict__ t1, const float* __restrict__ t2,
                                                 float* __restrict__ u, float* __restrict__ w) {
  const int tid = threadIdx.x;
  const size_t row = blockIdx.x;
  const float2 q = reinterpret_cast<const float2*>(Q + row * 512)[tid];
  const float2 k = reinterpret_cast<const float2*>(K + row * 512)[tid];
  const int c = tid * 2;
  __shared__ float redu[8][4], redw[8][4];
  const int wv = tid >> 6;
#pragma unroll
  for (int h = 0; h < 8; ++h) {
    float ua = q.x * t1[h * 512 + c] + q.y * t1[h * 512 + c + 1];
    float wa = k.x * t2[h * 512 + c] + k.y * t2[h * 512 + c + 1];
    ua = wave_sum(ua);
    wa = wave_sum(wa);
    if ((tid & 63) == 0) { redu[h][wv] = ua; redw[h][wv] = wa; }
  }
  __syncthreads();
  if (tid < 8)
    u[tid * 8192 + row] = redu[tid][0] + redu[tid][1] + redu[tid][2] + redu[tid][3];
  else if (tid < 16)
    w[(tid - 8) * 8192 + row] = redw[tid - 8][0] + redw[tid - 8][1] + redw[tid - 8][2] + redw[tid - 8][3];
}

// c[h] = bQ[h]·bK[h]. grid (8), 256 thr.
__global__ __launch_bounds__(256) void cvec(const float* __restrict__ bQ, const float* __restrict__ bK,
                                            float* __restrict__ c) {
  const int h = blockIdx.x, tid = threadIdx.x;
  const float2 a = reinterpret_cast<const float2*>(bQ + h * 512)[tid];
  const float2 b = reinterpret_cast<const float2*>(bK + h * 512)[tid];
  float acc = wave_sum(a.x * b.x + a.y * b.y);
  __shared__ float red[4];
  if ((tid & 63) == 0) red[tid >> 6] = acc;
  __syncthreads();
  if (tid == 0) c[h] = red[0] + red[1] + red[2] + red[3];
}

// bvo[e] = bo[e] + sum_hd wot[e][hd]*bV[hd]. grid (128), 256 thr, wave per e.
__global__ __launch_bounds__(256) void bvo_kernel(const __hip_bfloat16* __restrict__ wot,
                                                  const float* __restrict__ bV,
                                                  const float* __restrict__ bo,
                                                  float* __restrict__ bvo) {
  const int wv = threadIdx.x >> 6, lane = threadIdx.x & 63;
  const int e = blockIdx.x * 4 + wv;
  float acc = 0.f;
#pragma unroll
  for (int j = 0; j < 64; ++j) {
    const int hd = lane + 64 * j;
    acc += b2f(*(const unsigned short*)&wot[(size_t)e * 4096 + hd]) * bV[hd];
  }
  acc = wave_sum(acc);
  if (lane == 0) bvo[e] = bo[e] + acc;
}

// softmax over rows of sc[h][1024][1024] bf16, in place. grid (1024, 8), 256 thr.
__global__ __launch_bounds__(256) void softmax_bf16(__hip_bfloat16* __restrict__ sc) {
  const int tid = threadIdx.x;
  __hip_bfloat16* rowp = sc + ((size_t)blockIdx.y << 20) + ((size_t)blockIdx.x << 10);
  const ushort4 r = reinterpret_cast<const ushort4*>(rowp)[tid];
  const float v0 = b2f(r.x), v1 = b2f(r.y), v2 = b2f(r.z), v3 = b2f(r.w);
  __shared__ float red[8];
  float mx = fmaxf(fmaxf(v0, v1), fmaxf(v2, v3));
  mx = wave_max(mx);
  if ((tid & 63) == 0) red[tid >> 6] = mx;
  __syncthreads();
  mx = fmaxf(fmaxf(red[0], red[1]), fmaxf(red[2], red[3]));
  const float e0 = __expf(v0 - mx), e1 = __expf(v1 - mx);
  const float e2 = __expf(v2 - mx), e3 = __expf(v3 - mx);
  float s = wave_sum(e0 + e1 + e2 + e3);
  if ((tid & 63) == 0) red[4 + (tid >> 6)] = s;
  __syncthreads();
  const float inv = 1.f / (red[4] + red[5] + red[6] + red[7]);
  ushort4 o;
  o.x = f2b(e0 * inv); o.y = f2b(e1 * inv); o.z = f2b(e2 * inv); o.w = f2b(e3 * inv);
  reinterpret_cast<ushort4*>(rowp)[tid] = o;
}

// out = LN(Xa + Xb)*gamma + beta (rows of 512); optional bf16 copy. grid(8192), 256 thr.
__global__ __launch_bounds__(256) void add_ln(const float* __restrict__ Xa, const float* __restrict__ Xb,
                                              const float* __restrict__ gamma, const float* __restrict__ beta,
                                              float* __restrict__ out, __hip_bfloat16* __restrict__ outb) {
  const int tid = threadIdx.x;
  const size_t base = (size_t)blockIdx.x * Dd;
  const float2 a = reinterpret_cast<const float2*>(Xa + base)[tid];
  const float2 b = reinterpret_cast<const float2*>(Xb + base)[tid];
  const float r0 = a.x + b.x, r1 = a.y + b.y;
  float s = wave_sum(r0 + r1);
  float q = wave_sum(r0 * r0 + r1 * r1);
  __shared__ float rs[4], rq[4];
  if ((tid & 63) == 0) { rs[tid >> 6] = s; rq[tid >> 6] = q; }
  __syncthreads();
  const float mean = (rs[0] + rs[1] + rs[2] + rs[3]) * (1.f / Dd);
  const float msq = (rq[0] + rq[1] + rq[2] + rq[3]) * (1.f / Dd);
  const float inv = rsqrtf(msq - mean * mean + EPSf);
  const int c = tid * 2;
  const float y0 = (r0 - mean) * inv * gamma[c] + beta[c];
  const float y1 = (r1 - mean) * inv * gamma[c + 1] + beta[c + 1];
  out[base + c] = y0;
  out[base + c + 1] = y1;
  if (outb) {
    outb[base + c] = __float2bfloat16(y0);
    outb[base + c + 1] = __float2bfloat16(y1);
  }
}

extern "C" void kernel_launch(void* const* d_in, const int* in_sizes, int n_in,
                              void* d_out, int out_size, void* d_ws, size_t ws_size,
                              hipStream_t stream) {
  const float* Q = (const float*)d_in[0];
  const float* K = (const float*)d_in[1];
  const float* V = (const float*)d_in[2];
  const float* WQ = (const float*)d_in[3];
  const float* bQ = (const float*)d_in[4];
  const float* WK = (const float*)d_in[5];
  const float* bK = (const float*)d_in[6];
  const float* WV = (const float*)d_in[7];
  const float* bV = (const float*)d_in[8];
  const float* Wo = (const float*)d_in[9];
  const float* bo = (const float*)d_in[10];
  const float* W0 = (const float*)d_in[11];
  const float* b0 = (const float*)d_in[12];
  const float* g0 = (const float*)d_in[13];
  const float* be0 = (const float*)d_in[14];
  const float* m0 = (const float*)d_in[15];
  const float* v0 = (const float*)d_in[16];
  const float* a0 = (const float*)d_in[17];
  const float* W1 = (const float*)d_in[18];
  const float* b1 = (const float*)d_in[19];
  const float* g1 = (const float*)d_in[20];
  const float* be1 = (const float*)d_in[21];
  const float* m1 = (const float*)d_in[22];
  const float* v1 = (const float*)d_in[23];
  const float* a1 = (const float*)d_in[24];
  const float* W2 = (const float*)d_in[25];
  const float* b2 = (const float*)d_in[26];
  const float* ln0g = (const float*)d_in[27];
  const float* ln0b = (const float*)d_in[28];
  const float* ln1g = (const float*)d_in[29];
  const float* ln1b = (const float*)d_in[30];

  typedef __hip_bfloat16 bf;
  const size_t MB = 1u << 20;
  const size_t KB = 1u << 10;
  char* ws = (char*)d_ws;
  // -------- attention phase (peak exactly 120 MiB) --------
  bf* PR = (bf*)(ws);                      // [8192][4096]  0..64M   P, then R in place
  bf* wot = (bf*)(ws + 64 * MB);           // [512][4096]   64..68M  (precompute only)
  bf* sc = (bf*)(ws + 64 * MB);            // [8][1024][1024] 64..80M (loop; over wot)
  bf* qbf = (bf*)(ws + 80 * MB);           // [8192][512]   80..88M
  bf* kbf = (bf*)(ws + 88 * MB);           // 88..96M
  bf* vbft = (bf*)(ws + 96 * MB);          // [8][512][1024] 96..104M
  bf* wqbf = (bf*)(ws + 104 * MB);         // [8][512][512] 104..108M
  bf* wkbf = (bf*)(ws + 108 * MB);         // 108..112M
  bf* wvbf = (bf*)(ws + 112 * MB);         // 112..116M
  bf* wqkt = (bf*)(ws + 116 * MB);         // [8][512][512] 116..120M
  bf* wvot = (bf*)(ws + 104 * MB);         // [512][4096]   over wqbf (dead after wqkt)
  float* u = (float*)(ws + 108 * MB);      // [8][8192]     over wkbf (dead after wqkt)
  float* w = (float*)(ws + 108 * MB + 256 * KB);
  float* t1 = (float*)(ws + 108 * MB + 512 * KB);   // [8][512]
  float* t2 = (float*)(ws + 108 * MB + 528 * KB);
  float* cv = (float*)(ws + 108 * MB + 544 * KB);   // [8]
  float* bvo = (float*)(ws + 108 * MB + 548 * KB);  // [512]
  // -------- post-attention (dead-region reuse) --------
  float* mha = (float*)(ws + 64 * MB);     // [8192][512] f32 over sc
  float* xbuf = (float*)(ws + 80 * MB);    // over qbf
  bf* xb = (bf*)(ws + 96 * MB);            // over vbft
  bf* h0 = (bf*)(ws);                      // [8192][2048] over PR
  bf* h1 = (bf*)(ws + 32 * MB);
  float* ff = (float*)(ws + 64 * MB);      // over mha (dead after LN0)
  bf* w0t = (bf*)(ws + 104 * MB);          // over wvot (dead after mha)
  bf* w1t = (bf*)(ws + 106 * MB);          // 106..114M
  bf* w2t = (bf*)(ws + 114 * MB);          // 114..116M

  const size_t SD = (size_t)Sd * Dd;       // 524288
  const size_t DD = (size_t)Dd * Dd;       // 262144
  const size_t SS = (size_t)Sd * Sd;       // 1048576
  const float* np = nullptr;

  // ---- conversions ----
  conv3<<<dim3(2048, 2), 256, 0, stream>>>(Q, K, K, qbf, kbf, kbf);
  conv3<<<dim3(1024, 3), 256, 0, stream>>>(WQ, WK, WV, wqbf, wkbf, wvbf);
  tconv<<<dim3(8, 16, 8), 256, 0, stream>>>(V, vbft, Dd, Sd, SD, SD);
  tconv<<<dim3(8, 64, 1), 256, 0, stream>>>(Wo, wot, Dd, Hd * Dd, 0, 0);

  // ---- folded weights ----
  // wqkt[h][d'][d] = sum_e WK[h][d'][e]*WQ[h][d][e]  (= (Wq Wk^T)^T)
  bt_gemm<EPI_BF16><<<dim3(4, 4, 8), 256, 0, stream>>>(
      wkbf, Dd, 0, DD, wqbf, Dd, 0, DD, np, 0, 0,
      wqkt, Dd, 0, DD, Dd, 1.f, 3, np, np, np, np, np);
  // wvot[e][h*512+d] = sum_f wot[e][h*512+f]*WV[h][d][f]  (= (Wv_h Wo_h)^T stacked)
  bt_gemm<EPI_BF16><<<dim3(4, 4, 8), 256, 0, stream>>>(
      wot, Hd * Dd, 0, 512, wvbf, Dd, 0, DD, np, 0, 0,
      wvot, Hd * Dd, 0, 512, Dd, 1.f, 3, np, np, np, np, np);
  // ---- bias terms ----
  tvec<<<dim3(1024, 2), 256, 0, stream>>>(WQ, bK, WK, bQ, t1, t2);
  uw_kernel<<<Bd * Sd, 256, 0, stream>>>(Q, K, t1, t2, u, w);
  cvec<<<8, 256, 0, stream>>>(bQ, bK, cv);
  bvo_kernel<<<128, 256, 0, stream>>>(wot, bV, bo, bvo);

  // ---- P = Q @ Wqk (all heads): PR[s][h*512+d'] ----
  bt_gemm<EPI_BF16><<<dim3(4, 64, 8), 256, 0, stream>>>(
      qbf, Dd, 0, 0, wqkt, Dd, 0, DD, np, 0, 0,
      PR, Hd * Dd, 0, 512, Dd, 1.f, 3, np, np, np, np, np);

  // ---- per-batch: scores -> softmax -> R (in place over P) ----
  for (int b = 0; b < Bd; ++b) {
    const size_t rowoff = (size_t)b * Sd * Hd * Dd;
    bt_gemm<EPI_SCORES><<<dim3(8, 8, 8), 256, 0, stream>>>(
        PR + rowoff, Hd * Dd, 0, 512, kbf + b * SD, Dd, 0, 0, np, 0, 0,
        sc, Sd, 0, SS, Dd, 1.f / (float)Dd, 3,
        u + b * Sd, w + b * Sd, cv, np, np);
    softmax_bf16<<<dim3(Sd, Hd), 256, 0, stream>>>(sc);
    // R[s][h*512+d] = sum_t attn[h][s][t] * V[b][t][d]
    bt_gemm<EPI_BF16><<<dim3(4, 8, 8), 256, 0, stream>>>(
        sc, Sd, 0, SS, vbft + b * SD, Sd, 0, 0, np, 0, 0,
        PR + rowoff, Hd * Dd, 0, 512, Sd, 1.f, 3, np, np, np, np, np);
  }

  // ---- mha = Rcat @ Wvo + bvo ----
  bt_gemm<EPI_F32><<<dim3(4, 64, 1), 256, 0, stream>>>(
      PR, Hd * Dd, 0, 0, wvot, Hd * Dd, 0, 0, bvo, 0, 0,
      mha, Dd, 0, 0, Hd * Dd, 1.f, 0, np, np, np, np, np);
  add_ln<<<Bd * Sd, 256, 0, stream>>>(Q, mha, ln0g, ln0b, xbuf, xb);

  // ---- FF ----
  tconv<<<dim3(32, 8, 1), 256, 0, stream>>>(W0, w0t, Fd, Dd, 0, 0);
  tconv<<<dim3(32, 32, 1), 256, 0, stream>>>(W1, w1t, Fd, Fd, 0, 0);
  tconv<<<dim3(8, 32, 1), 256, 0, stream>>>(W2, w2t, Dd, Fd, 0, 0);

  bt_gemm<EPI_BNPRELU><<<dim3(16, 64, 1), 256, 0, stream>>>(
      xb, Dd, 0, 0, w0t, Dd, 0, 0, b0, 0, 0,
      h0, Fd, 0, 0, Dd, 1.f, 0, g0, be0, m0, v0, a0);
  bt_gemm<EPI_BNPRELU><<<dim3(16, 64, 1), 256, 0, stream>>>(
      h0, Fd, 0, 0, w1t, Fd, 0, 0, b1, 0, 0,
      h1, Fd, 0, 0, Fd, 1.f, 0, g1, be1, m1, v1, a1);
  bt_gemm<EPI_F32><<<dim3(4, 64, 1), 256, 0, stream>>>(
      h1, Fd, 0, 0, w2t, Fd, 0, 0, b2, 0, 0,
      ff, Dd, 0, 0, Fd, 1.f, 0, np, np, np, np, np);
  add_ln<<<Bd * Sd, 256, 0, stream>>>(xbuf, ff, ln1g, ln1b, (float*)d_out, nullptr);
}